// Round 1
// baseline (189.014 us; speedup 1.0000x reference)
//
#include <hip/hip_runtime.h>
#include <hip/hip_bf16.h>

typedef unsigned int u32;
typedef __bf16 bf16x8 __attribute__((ext_vector_type(8)));
typedef float  f32x4  __attribute__((ext_vector_type(4)));

#define NTOK 8192
#define DIM  512
#define FDIM 2048
#define NEXP 8

// ---- workspace layout (bytes) ----
#define OFF_W1T   0ull                 // bf16 [E][F][D]  16,777,216 B
#define OFF_W2T   16777216ull          // bf16 [E][D][F]  16,777,216 B
#define OFF_XB    33554432ull          // bf16 [N][D]      8,388,608 B
#define OFF_H     41943040ull          // bf16 [N][F]     33,554,432 B
#define OFF_SCALE 75497472ull          // f32  [N]            32,768 B
#define OFF_CNT   75530240ull          // int  [E]
#define OFF_LIST  75530272ull          // int  [E][N]        262,144 B

__device__ __forceinline__ u32 rotl32(u32 x, int r) { return (x << r) | (x >> (32 - r)); }

__device__ __forceinline__ void threefry2x32(u32 k0, u32 k1, u32 x0, u32 x1,
                                             u32& y0, u32& y1) {
  u32 ks2 = k0 ^ k1 ^ 0x1BD11BDAu;
  x0 += k0; x1 += k1;
#define TF_RND(r) { x0 += x1; x1 = rotl32(x1, r); x1 ^= x0; }
  TF_RND(13) TF_RND(15) TF_RND(26) TF_RND(6)
  x0 += k1;  x1 += ks2 + 1u;
  TF_RND(17) TF_RND(29) TF_RND(16) TF_RND(24)
  x0 += ks2; x1 += k0 + 2u;
  TF_RND(13) TF_RND(15) TF_RND(26) TF_RND(6)
  x0 += k0;  x1 += k1 + 3u;
  TF_RND(17) TF_RND(29) TF_RND(16) TF_RND(24)
  x0 += k1;  x1 += ks2 + 4u;
  TF_RND(13) TF_RND(15) TF_RND(26) TF_RND(6)
  x0 += ks2; x1 += k0 + 5u;
#undef TF_RND
  y0 = x0; y1 = x1;
}

// JAX partitionable threefry 32-bit bits for flat index j, key (0,42):
// bits = y0 ^ y1 of threefry2x32(key, (hi=0, lo=j))
__device__ __forceinline__ float jax_uniform(u32 j) {
  u32 y0, y1;
  threefry2x32(0u, 42u, 0u, j, y0, y1);
  u32 bits = y0 ^ y1;
  return __uint_as_float((bits >> 9) | 0x3F800000u) - 1.0f;
}

__device__ __forceinline__ unsigned short f2b(float f) {
  u32 u = __float_as_uint(f);
  u32 r = (u + 0x7FFFu + ((u >> 16) & 1u)) >> 16;
  return (unsigned short)r;
}

// ---------------- router ----------------
__global__ __launch_bounds__(256) void router_kernel(
    const float* __restrict__ attr, const float* __restrict__ Wr,
    const float* __restrict__ br, float* __restrict__ scale,
    int* __restrict__ cnt, int* __restrict__ list) {
  int i = blockIdx.x * 256 + threadIdx.x;
  if (i >= NTOK) return;
  float a[3];
#pragma unroll
  for (int c = 0; c < 3; ++c) {
    float u = jax_uniform((u32)(3 * i + c));
    a[c] = attr[3 * i + c] * ((1.0f + 0.01f) - 2.0f * 0.01f * u);
  }
  float logits[NEXP];
#pragma unroll
  for (int e = 0; e < NEXP; ++e)
    logits[e] = br[e] + a[0] * Wr[0 * NEXP + e] + a[1] * Wr[1 * NEXP + e] + a[2] * Wr[2 * NEXP + e];
  float m = logits[0]; int am = 0;
#pragma unroll
  for (int e = 1; e < NEXP; ++e)
    if (logits[e] > m) { m = logits[e]; am = e; }
  float s = 0.f;
#pragma unroll
  for (int e = 0; e < NEXP; ++e) s += __expf(logits[e] - m) * 0.0f + expf(logits[e] - m);
  scale[i] = 1.0f / s;
  int pos = atomicAdd(&cnt[am], 1);
  list[am * NTOK + pos] = i;
}

// ---------------- x -> bf16 ----------------
__global__ __launch_bounds__(256) void convert_x_kernel(const float4* __restrict__ in,
                                                        uint2* __restrict__ out) {
  int i = blockIdx.x * 256 + threadIdx.x;
  if (i >= NTOK * DIM / 4) return;
  float4 v = in[i];
  u32 lo = (u32)f2b(v.x) | ((u32)f2b(v.y) << 16);
  u32 hi = (u32)f2b(v.z) | ((u32)f2b(v.w) << 16);
  out[i] = make_uint2(lo, hi);
}

// ---------------- transpose fp32 [e][R][C] -> bf16 [e][C][R] ----------------
__global__ __launch_bounds__(256) void transpose_bf16_kernel(
    const float* __restrict__ in, unsigned short* __restrict__ out, int R, int C) {
  int e = blockIdx.z;
  in  += (size_t)e * R * C;
  out += (size_t)e * R * C;
  __shared__ float tile[32][33];
  int c0 = blockIdx.x * 32, r0 = blockIdx.y * 32;
  int tr = threadIdx.x >> 5;   // 0..7
  int tc = threadIdx.x & 31;
#pragma unroll
  for (int it = 0; it < 4; ++it)
    tile[tr + it * 8][tc] = in[(size_t)(r0 + tr + it * 8) * C + c0 + tc];
  __syncthreads();
#pragma unroll
  for (int it = 0; it < 4; ++it)
    out[(size_t)(c0 + tr + it * 8) * R + r0 + tc] = f2b(tile[tc][tr + it * 8]);
}

// ---------------- grouped GEMM ----------------
__device__ __forceinline__ void load_lds16(const void* g, void* l) {
  __builtin_amdgcn_global_load_lds(
      (const __attribute__((address_space(1))) u32*)g,
      (__attribute__((address_space(3))) u32*)l, 16, 0, 0);
}

// C[p, n] = sum_k A[list[p], k] * Bt[e][n][k]; epilogue per template.
template <int KK, int NN, bool G1>
__global__ __launch_bounds__(256) void moe_gemm_kernel(
    const unsigned short* __restrict__ A,    // bf16 [*][KK] rows by token id
    const unsigned short* __restrict__ Bt,   // bf16 [E][NN][KK]
    const float* __restrict__ bias,          // [E][NN]
    const int* __restrict__ list,            // [E][NTOK]
    const int* __restrict__ cnt,             // [E]
    const float* __restrict__ scale,         // [N]
    unsigned short* __restrict__ Hout,       // bf16 [N][FDIM]   (G1)
    float* __restrict__ Yout) {              // f32  [N][DIM]    (!G1)
  const int e = blockIdx.z;
  const int cn = cnt[e];
  const int m0 = blockIdx.y * 128;
  if (m0 >= cn) return;
  const int n0 = blockIdx.x * 128;
  const int tid = threadIdx.x;
  const int lane = tid & 63;
  const int wid = tid >> 6;
  const int wm = wid >> 1, wn = wid & 1;

  __shared__ unsigned short Asm[128 * 32];
  __shared__ unsigned short Bsm[128 * 32];

  const int* mylist = list + e * NTOK;
  const unsigned short* Be = Bt + (size_t)e * NN * KK;

  // staging source offsets (XOR slot-swizzled LDS layout, inverse on source)
  int aoff[2], boff[2], ldso[2];
#pragma unroll
  for (int j = 0; j < 2; ++j) {
    int o = j * 4096 + tid * 16;       // linear LDS byte offset
    int row = o >> 6;                  // 0..127
    int slot = (o >> 4) & 3;
    int g = (slot - (row >> 1)) & 3;   // which 8-elem k-group lives here
    int p = m0 + row; if (p >= cn) p = cn - 1;
    int tok = mylist[p];
    aoff[j] = tok * KK + g * 8;
    boff[j] = (n0 + row) * KK + g * 8;
    ldso[j] = o;
  }

  f32x4 acc[4][4];
#pragma unroll
  for (int i = 0; i < 4; ++i)
#pragma unroll
    for (int j = 0; j < 4; ++j) acc[i][j] = (f32x4){0.f, 0.f, 0.f, 0.f};

  int a_addr[4], b_addr[4];
#pragma unroll
  for (int mi = 0; mi < 4; ++mi) {
    int row = wm * 64 + mi * 16 + (lane & 15);
    int gp = ((lane >> 4) + (row >> 1)) & 3;
    a_addr[mi] = row * 32 + gp * 8;
  }
#pragma unroll
  for (int ni = 0; ni < 4; ++ni) {
    int row = wn * 64 + ni * 16 + (lane & 15);
    int gp = ((lane >> 4) + (row >> 1)) & 3;
    b_addr[ni] = row * 32 + gp * 8;
  }

  for (int kt = 0; kt < KK / 32; ++kt) {
#pragma unroll
    for (int j = 0; j < 2; ++j) {
      load_lds16(A + aoff[j] + kt * 32, (char*)Asm + ldso[j]);
      load_lds16(Be + boff[j] + kt * 32, (char*)Bsm + ldso[j]);
    }
    __syncthreads();
    bf16x8 af[4], bfr[4];
#pragma unroll
    for (int mi = 0; mi < 4; ++mi) af[mi] = *(const bf16x8*)(Asm + a_addr[mi]);
#pragma unroll
    for (int ni = 0; ni < 4; ++ni) bfr[ni] = *(const bf16x8*)(Bsm + b_addr[ni]);
#pragma unroll
    for (int mi = 0; mi < 4; ++mi)
#pragma unroll
      for (int ni = 0; ni < 4; ++ni)
        acc[mi][ni] = __builtin_amdgcn_mfma_f32_16x16x32_bf16(af[mi], bfr[ni], acc[mi][ni], 0, 0, 0);
    __syncthreads();
  }

  // epilogue: D layout col = lane&15, row = (lane>>4)*4 + i
  const int colb = n0 + wn * 64 + (lane & 15);
  float bia[4];
#pragma unroll
  for (int ni = 0; ni < 4; ++ni) bia[ni] = bias[(size_t)e * NN + colb + ni * 16];
#pragma unroll
  for (int mi = 0; mi < 4; ++mi) {
#pragma unroll
    for (int i = 0; i < 4; ++i) {
      int p = m0 + wm * 64 + mi * 16 + (lane >> 4) * 4 + i;
      if (p < cn) {
        int tok = mylist[p];
        if constexpr (G1) {
#pragma unroll
          for (int ni = 0; ni < 4; ++ni) {
            float v = acc[mi][ni][i] + bia[ni];
            float g = 0.5f * v * (1.0f + erff(v * 0.70710678118654752f));
            Hout[(size_t)tok * NN + colb + ni * 16] = f2b(g);
          }
        } else {
          float s = scale[tok];
#pragma unroll
          for (int ni = 0; ni < 4; ++ni) {
            float v = (acc[mi][ni][i] + bia[ni]) * s;
            Yout[(size_t)tok * NN + colb + ni * 16] = v;
          }
        }
      }
    }
  }
}

extern "C" void kernel_launch(void* const* d_in, const int* in_sizes, int n_in,
                              void* d_out, int out_size, void* d_ws, size_t ws_size,
                              hipStream_t stream) {
  const float* x    = (const float*)d_in[0];
  const float* attr = (const float*)d_in[1];
  const float* Wr   = (const float*)d_in[2];
  const float* br   = (const float*)d_in[3];
  const float* W1   = (const float*)d_in[4];
  const float* b1   = (const float*)d_in[5];
  const float* W2   = (const float*)d_in[6];
  const float* b2   = (const float*)d_in[7];
  float* out = (float*)d_out;
  char* ws = (char*)d_ws;

  unsigned short* W1t = (unsigned short*)(ws + OFF_W1T);
  unsigned short* W2t = (unsigned short*)(ws + OFF_W2T);
  unsigned short* xb  = (unsigned short*)(ws + OFF_XB);
  unsigned short* H   = (unsigned short*)(ws + OFF_H);
  float* scale        = (float*)(ws + OFF_SCALE);
  int* cnt            = (int*)(ws + OFF_CNT);
  int* list           = (int*)(ws + OFF_LIST);

  hipMemsetAsync(cnt, 0, NEXP * sizeof(int), stream);
  router_kernel<<<NTOK / 256, 256, 0, stream>>>(attr, Wr, br, scale, cnt, list);
  convert_x_kernel<<<(NTOK * DIM / 4) / 256, 256, 0, stream>>>((const float4*)x, (uint2*)xb);
  // W1 [E][512][2048] -> W1t [E][2048][512]
  transpose_bf16_kernel<<<dim3(FDIM / 32, DIM / 32, NEXP), 256, 0, stream>>>(W1, W1t, DIM, FDIM);
  // W2 [E][2048][512] -> W2t [E][512][2048]
  transpose_bf16_kernel<<<dim3(DIM / 32, FDIM / 32, NEXP), 256, 0, stream>>>(W2, W2t, FDIM, DIM);

  moe_gemm_kernel<DIM, FDIM, true><<<dim3(FDIM / 128, NTOK / 128, NEXP), 256, 0, stream>>>(
      xb, W1t, b1, list, cnt, scale, H, nullptr);
  moe_gemm_kernel<FDIM, DIM, false><<<dim3(DIM / 128, NTOK / 128, NEXP), 256, 0, stream>>>(
      H, W2t, b2, list, cnt, scale, nullptr, out);
}